// Round 11
// baseline (282.774 us; speedup 1.0000x reference)
//
#include <hip/hip_runtime.h>
#include <math.h>

// ---------------------------------------------------------------------------
// SRModel. Round 11 = Round 10 + x/h stored in MFMA B-fragment-linear LDS
// layout [pt][ks][lane][e]: B ds_read_b128 becomes lane-linear (byte l*16,
// conflict-free). Round-10 diagnosis: the persistent 1.2e7 bank conflicts are
// the GEMM B reads (row-stride 512B -> bank = f(k') only -> 8-way). Epilogue
// writes scatter to (lane_dst, e0) with ks = wave id. Value-identical.
// ---------------------------------------------------------------------------

#define HL 80
#define WL 80
#define HH 320
#define WH 320
#define NPIX (HH*WH)      // 102400
#define LRPIX (HL*WL)     // 6400
#define HID 256
#define K2 49

typedef _Float16 half8 __attribute__((ext_vector_type(8)));
typedef _Float16 half4 __attribute__((ext_vector_type(4)));
typedef float f32x4 __attribute__((ext_vector_type(4)));

__device__ __forceinline__ float gelu_f(float x) {
  float u = __builtin_fmaf(0.044715f*x, x*x, x);
  float e = __expf(-1.5957691216057308f * u);
  return x * __builtin_amdgcn_rcpf(1.0f + e);
}

__device__ __forceinline__ float keys_cubic(float x) {
  x = fabsf(x);
  if (x >= 2.0f) return 0.0f;
  if (x >= 1.0f) return ((-0.5f*x + 2.5f)*x - 4.0f)*x + 2.0f;
  return ((1.5f*x - 2.5f)*x)*x + 1.0f;
}

// -------- encoder conv0: lr NCHW [3][LRPIX] -> NHWC out [LRPIX][64] --------
__global__ void enc_conv0(const float* __restrict__ in, const float* __restrict__ w,
                          const float* __restrict__ bias, float* __restrict__ out) {
  __shared__ float wl[216];
  int tid = threadIdx.x;
  int chunk = blockIdx.y;
  if (tid < 216) {
    int o = tid/27, r = tid - o*27, ic = r/9, tap = r - ic*9;
    wl[tap*24 + ic*8 + o] = w[((chunk*8+o)*3+ic)*9 + tap];
  }
  __syncthreads();
  int pix = blockIdx.x*blockDim.x + tid;
  int y = pix / WL, x = pix % WL;
  float acc[8];
#pragma unroll
  for (int o=0;o<8;o++) acc[o] = bias[chunk*8+o];
#pragma unroll
  for (int ky=0; ky<3; ky++) {
    int yy = y+ky-1;
    if (yy < 0 || yy >= HL) continue;
#pragma unroll
    for (int kx=0; kx<3; kx++) {
      int xx = x+kx-1;
      if (xx < 0 || xx >= WL) continue;
      int o0 = yy*WL+xx, tap = ky*3+kx;
#pragma unroll
      for (int ic=0; ic<3; ic++) {
        float v = in[ic*LRPIX + o0];
        const f32x4* wb = (const f32x4*)&wl[tap*24 + ic*8];
        f32x4 w0 = wb[0], w1 = wb[1];
#pragma unroll
        for (int o=0;o<4;o++) { acc[o] += v*w0[o]; acc[o+4] += v*w1[o]; }
      }
    }
  }
#pragma unroll
  for (int o=0;o<8;o++)
    out[pix*64 + chunk*8 + o] = gelu_f(acc[o]);
}

// -------- encoder hidden conv: NHWC in -> NHWC out; LDS weights ------------
__global__ void enc_convh(const float* __restrict__ in, const float* __restrict__ w,
                          const float* __restrict__ bias, float* __restrict__ out) {
  __shared__ float wl[4608];
  int tid = threadIdx.x;
  int chunk = blockIdx.y;
  const float* wsrc = w + chunk*8*576;     // [8 oc][64 ic][9 tap]
#pragma unroll
  for (int i=0;i<36;i++) {
    int idx = tid + i*128;
    int o = idx/576, r = idx - o*576, ic = r/9, tap = r - ic*9;
    wl[tap*512 + ic*8 + o] = wsrc[idx];
  }
  __syncthreads();
  int pix = blockIdx.x*128 + tid;
  int y = pix / WL, x = pix % WL;
  float acc[8];
#pragma unroll
  for (int o=0;o<8;o++) acc[o] = bias[chunk*8+o];
#pragma unroll
  for (int ky=0; ky<3; ky++) {
    int yy = y+ky-1;
    if (yy < 0 || yy >= HL) continue;
#pragma unroll
    for (int kx=0; kx<3; kx++) {
      int xx = x+kx-1;
      if (xx < 0 || xx >= WL) continue;
      const f32x4* src = (const f32x4*)&in[(yy*WL+xx)*64];
      const float* wt = &wl[(ky*3+kx)*512];
#pragma unroll
      for (int icv=0; icv<16; icv++) {
        f32x4 v = src[icv];
#pragma unroll
        for (int j=0;j<4;j++) {
          const f32x4* wb = (const f32x4*)&wt[(icv*4+j)*8];
          f32x4 w0 = wb[0], w1 = wb[1];
#pragma unroll
          for (int o=0;o<4;o++) { acc[o] += v[j]*w0[o]; acc[4+o] += v[j]*w1[o]; }
        }
      }
    }
  }
#pragma unroll
  for (int o=0;o<8;o++)
    out[pix*64 + chunk*8 + o] = gelu_f(acc[o]);
}

// ---------------- bicubic upsample (matches jax.image.resize 'cubic') ------
__global__ void bicubic_up(const float* __restrict__ lr, float* __restrict__ up) {
  int id = blockIdx.x*blockDim.x + threadIdx.x;
  if (id >= 3*NPIX) return;
  int c = id / NPIX, p = id % NPIX;
  int hy = p / WH, hx = p % WH;
  float sx = (hx+0.5f)*0.25f - 0.5f;
  float sy = (hy+0.5f)*0.25f - 0.5f;
  int bx = (int)floorf(sx), by = (int)floorf(sy);
  float wx[4], wy[4];
  int ix[4], iy[4];
  float sumx = 0.f, sumy = 0.f;
#pragma unroll
  for (int i=0;i<4;i++) {
    int j = bx-1+i;
    float wv = (j>=0 && j<WL) ? keys_cubic(sx - (float)j) : 0.f;
    wx[i] = wv; ix[i] = min(max(j,0), WL-1); sumx += wv;
    j = by-1+i;
    wv = (j>=0 && j<HL) ? keys_cubic(sy - (float)j) : 0.f;
    wy[i] = wv; iy[i] = min(max(j,0), HL-1); sumy += wv;
  }
  float inx = __builtin_amdgcn_rcpf(sumx), iny = __builtin_amdgcn_rcpf(sumy);
  const float* src = lr + c*LRPIX;
  float acc = 0.f;
#pragma unroll
  for (int i=0;i<4;i++) {
    float rowv = 0.f;
#pragma unroll
    for (int j=0;j<4;j++) rowv += wx[j]*src[iy[i]*WL + ix[j]];
    acc += wy[i]*rowv;
  }
  up[c*NPIX + p] = acc * inx * iny;
}

// ------- weight prep: fp32 -> fp16, packed in MFMA fragment order ----------
__global__ void prep_weights(const float* __restrict__ w0, const float* __restrict__ wh,
                             const float* __restrict__ kw, const float* __restrict__ gw,
                             _Float16* __restrict__ out) {
  int idx = blockIdx.x*blockDim.x + threadIdx.x;
  int e = idx & 7, lane = (idx>>3)&63;
  int kf = (lane>>4)*8 + e;
  int nf = lane & 15;
  if (idx < 32768) {
    int t = idx >> 9;
    int kt = t & 3, nt = t >> 2;
    int k = kt*32 + kf, n = nt*16 + nf;
    out[idx] = (_Float16)((k < 106) ? w0[k*HID + n] : 0.f);
  } else if (idx < 32768 + 4*65536) {
    int r = idx - 32768;
    int L = r >> 16; r &= 65535;
    int t = r >> 9;
    int kt = t & 7, nt = t >> 3;
    int k = kt*32 + kf, n = nt*16 + nf;
    out[idx] = (_Float16)wh[(L*HID + k)*HID + n];
  } else if (idx < 32768 + 5*65536) {
    int r = idx - (32768 + 4*65536);
    int t = r >> 9;
    int kt = t & 7, nt = t >> 3;
    int k = kt*32 + kf, n = nt*16 + nf;
    float v = (n < 196) ? kw[k*196 + n] : ((n < 200) ? gw[k*4 + (n-196)] : 0.f);
    out[idx] = (_Float16)v;
  }
}

// ---------------- fused per-pixel MLP (MFMA) + softmax + 7x7 sum ------------
// x/h live in LDS in B-fragment-linear order [pt][ks][lane][e]:
//   buf[((pt*NKS+ks)*64 + lane)*8 + e] = val[pixel=pt*16+(lane&15)]
//                                           [k = ks*32+(lane>>4)*8+e]
#define PMT 512
__global__ __launch_bounds__(PMT, 4)
void pixel_mlp2(const float* __restrict__ f, const float* __restrict__ lr,
                const _Float16* __restrict__ Wt0, const float* __restrict__ b0,
                const _Float16* __restrict__ Wth, const float* __restrict__ bh,
                const _Float16* __restrict__ Whd, const float* __restrict__ kb,
                const float* __restrict__ gb, float* __restrict__ res0) {
  __shared__ _Float16 smem[8192 + 16384 + 16384];   // x | hA | hB  = 80 KB
  _Float16* x_lds = smem;            // frag layout, NKS=4
  _Float16* hA    = smem + 8192;     // frag layout, NKS=8
  _Float16* hB    = smem + 8192 + 16384;
  _Float16* kbuf  = hB;              // alias: hB dead when kbuf written

  const int tid = threadIdx.x;
  const int lane = tid & 63;
  const int wave = tid >> 6;
  const int n0 = blockIdx.x * 64;
  const int hy = n0 / WH;                       // block-uniform (64 | 320)
  const int hx0 = n0 % WH;
  const float ly = (hy+0.5f)*0.25f - 0.5f;
  const int byi = min(max((int)floorf(ly),0), HL-1);
  const float fy = ly - floorf(ly);
  const float hyn = (hy+0.5f)/320.0f*2.0f - 1.0f;   // reference rounding path

  // ---- Phase A, part 1: cfeat (k<64) from NHWC f -> frag layout ----
#pragma unroll
  for (int i = 0; i < 8; i++) {
    int p = (tid>>6) + i*8;            // wave-uniform pixel
    int k = lane;
    int hx = hx0 + p;
    float lx = (hx+0.5f)*0.25f - 0.5f;
    int bxi = min(max((int)floorf(lx),0), WL-1);
    float v = f[(byi*WL + bxi)*64 + k];
    int ld = (p & 15) | (((k >> 3) & 3) << 4);
    x_lds[(((p>>4)*4 + (k>>5))*64 + ld)*8 + (k & 7)] = (_Float16)v;
  }
  // ---- Phase A, part 2: PE (libm trig, reference-exact fp32 rounding) ----
#pragma unroll
  for (int i = 0; i < 8; i++) {
    int p = (tid>>6) + i*8;
    int k = 64 + lane;
    int hx = hx0 + p;
    float v = 0.f;
    if (k < 104) {
      int band = (k-64) >> 2, r = (k-64) & 3;
      float freq = (float)(1<<band) * 3.14159265358979323846f;
      float hxn = (hx+0.5f)/320.0f*2.0f - 1.0f;
      float arg = ((r<2) ? hxn : hyn) * freq;
      v = (r&1) ? cosf(arg) : sinf(arg);
    } else if (k == 104) {
      float lx = (hx+0.5f)*0.25f - 0.5f;
      v = lx - floorf(lx);
    } else if (k == 105) {
      v = fy;
    }
    int ld = (p & 15) | (((k >> 3) & 3) << 4);
    x_lds[(((p>>4)*4 + (k>>5))*64 + ld)*8 + (k & 7)] = (_Float16)v;
  }
  __syncthreads();

  const int col  = lane & 15;
  const int g    = lane >> 4;
  const int rbase = g*4;
  // epilogue scatter constants: lane_dst for nt=0/1, e0
  const int ld0 = (lane & 15) | (((g>>1)    ) << 4);        // nt=0: (0+g/2)&3
  const int ld1 = (lane & 15) | (((2 + (g>>1)) & 3) << 4);  // nt=1
  const int e0  = 4*(g & 1);

  f32x4 acc[2][4];
  const f32x4 vzero = {0.f,0.f,0.f,0.f};
  const half8* A0 = (const half8*)Wt0;
  const half8* AH = (const half8*)Whd;

  // ---- layer 0: W0(A) x x(B) -> hA (frag NKS=8) ----
#pragma unroll
  for (int nt=0;nt<2;nt++)
#pragma unroll
    for (int pt=0;pt<4;pt++) acc[nt][pt] = vzero;
#pragma unroll
  for (int ks=0; ks<4; ks++) {
    half8 aw[2], bx[4];
#pragma unroll
    for (int nt=0;nt<2;nt++)
      aw[nt] = A0[((wave*2+nt)*4 + ks)*64 + lane];
#pragma unroll
    for (int pt=0;pt<4;pt++)
      bx[pt] = *(const half8*)&x_lds[((pt*4 + ks)*64 + lane)*8];   // linear
#pragma unroll
    for (int nt=0;nt<2;nt++)
#pragma unroll
      for (int pt=0;pt<4;pt++)
        acc[nt][pt] = __builtin_amdgcn_mfma_f32_16x16x32_f16(aw[nt], bx[pt], acc[nt][pt], 0,0,0);
  }
#pragma unroll
  for (int nt=0;nt<2;nt++) {
    int nbase = wave*32 + nt*16 + rbase;
    f32x4 bb = *(const f32x4*)&b0[nbase];
    int ld = nt ? ld1 : ld0;
#pragma unroll
    for (int pt=0;pt<4;pt++) {
      half4 hv;
      hv[0] = (_Float16)gelu_f(acc[nt][pt][0] + bb[0]);
      hv[1] = (_Float16)gelu_f(acc[nt][pt][1] + bb[1]);
      hv[2] = (_Float16)gelu_f(acc[nt][pt][2] + bb[2]);
      hv[3] = (_Float16)gelu_f(acc[nt][pt][3] + bb[3]);
      *(half4*)&hA[((pt*8 + wave)*64 + ld)*8 + e0] = hv;
    }
  }
  __syncthreads();

  // ---- 4 hidden layers: ping-pong hA <-> hB (frag layout, NKS=8) ----
  for (int L=0; L<4; L++) {
    const _Float16* hs = (L & 1) ? hB : hA;
    _Float16*       hd = (L & 1) ? hA : hB;
    const half8* AL = (const half8*)(Wth + L*65536);
#pragma unroll
    for (int nt=0;nt<2;nt++)
#pragma unroll
      for (int pt=0;pt<4;pt++) acc[nt][pt] = vzero;
#pragma unroll
    for (int ks=0; ks<8; ks++) {
      half8 aw[2], bx[4];
#pragma unroll
      for (int nt=0;nt<2;nt++)
        aw[nt] = AL[((wave*2+nt)*8 + ks)*64 + lane];
#pragma unroll
      for (int pt=0;pt<4;pt++)
        bx[pt] = *(const half8*)&hs[((pt*8 + ks)*64 + lane)*8];    // linear
#pragma unroll
      for (int nt=0;nt<2;nt++)
#pragma unroll
        for (int pt=0;pt<4;pt++)
          acc[nt][pt] = __builtin_amdgcn_mfma_f32_16x16x32_f16(aw[nt], bx[pt], acc[nt][pt], 0,0,0);
    }
#pragma unroll
    for (int nt=0;nt<2;nt++) {
      int nbase = wave*32 + nt*16 + rbase;
      f32x4 bb = *(const f32x4*)&bh[L*HID + nbase];
      int ld = nt ? ld1 : ld0;
#pragma unroll
      for (int pt=0;pt<4;pt++) {
        half4 hv;
        hv[0] = (_Float16)gelu_f(acc[nt][pt][0] + bb[0]);
        hv[1] = (_Float16)gelu_f(acc[nt][pt][1] + bb[1]);
        hv[2] = (_Float16)gelu_f(acc[nt][pt][2] + bb[2]);
        hv[3] = (_Float16)gelu_f(acc[nt][pt][3] + bb[3]);
        *(half4*)&hd[((pt*8 + wave)*64 + ld)*8 + e0] = hv;
      }
    }
    __syncthreads();
  }

  // ---- head: Whd(A) x hA(B) -> 200 logits/pixel into kbuf[pix][208] ----
#pragma unroll
  for (int nt=0;nt<2;nt++)
#pragma unroll
    for (int pt=0;pt<4;pt++) acc[nt][pt] = vzero;
#pragma unroll
  for (int ks=0; ks<8; ks++) {
    half8 aw[2], bx[4];
#pragma unroll
    for (int nt=0;nt<2;nt++)
      aw[nt] = AH[((wave*2+nt)*8 + ks)*64 + lane];
#pragma unroll
    for (int pt=0;pt<4;pt++)
      bx[pt] = *(const half8*)&hA[((pt*8 + ks)*64 + lane)*8];      // linear
#pragma unroll
    for (int nt=0;nt<2;nt++)
#pragma unroll
      for (int pt=0;pt<4;pt++)
        acc[nt][pt] = __builtin_amdgcn_mfma_f32_16x16x32_f16(aw[nt], bx[pt], acc[nt][pt], 0,0,0);
  }
#pragma unroll
  for (int nt=0;nt<2;nt++) {
    int jb = wave*32 + nt*16 + rbase;
    if (jb < 200) {
      const float* bp = (jb < 196) ? (kb + jb) : (gb + (jb - 196));
      f32x4 bb = *(const f32x4*)bp;
#pragma unroll
      for (int pt=0;pt<4;pt++) {
        int pix = pt*16 + col;
        half4 kv;
        kv[0] = (_Float16)(acc[nt][pt][0] + bb[0]);
        kv[1] = (_Float16)(acc[nt][pt][1] + bb[1]);
        kv[2] = (_Float16)(acc[nt][pt][2] + bb[2]);
        kv[3] = (_Float16)(acc[nt][pt][3] + bb[3]);
        *(half4*)&kbuf[pix*208 + jb] = kv;
      }
    }
  }
  __syncthreads();

  // ---- Phase E (tap-split): thread q owns kernel row q (7 taps, 4 heads) ---
  {
    int p = tid >> 3, q = tid & 7;
    int hx = hx0 + p;
    float lx = (hx+0.5f)*0.25f - 0.5f;
    int bxi = min(max((int)floorf(lx),0), WL-1);
    const _Float16* kp = &kbuf[p*208];
    // gate softmax (redundant on 8 threads)
    float g0=(float)kp[196], g1=(float)kp[197], g2=(float)kp[198], g3=(float)kp[199];
    float gm = fmaxf(fmaxf(g0,g1), fmaxf(g2,g3));
    g0=__expf(g0-gm); g1=__expf(g1-gm); g2=__expf(g2-gm); g3=__expf(g3-gm);
    float gs = __builtin_amdgcn_rcpf(g0+g1+g2+g3);
    float gate[4] = {g0*gs, g1*gs, g2*gs, g3*gs};
    // load 28 logits into regs + per-head local max
    float e[4][7];
    float m[4];
#pragma unroll
    for (int h=0;h<4;h++) m[h] = -1e30f;
    if (q < 7) {
#pragma unroll
      for (int h=0;h<4;h++)
#pragma unroll
        for (int i=0;i<7;i++) {
          float v = (float)kp[h*K2 + q*7 + i];
          e[h][i] = v;
          m[h] = fmaxf(m[h], v);
        }
    }
#pragma unroll
    for (int h=0;h<4;h++) {
      m[h] = fmaxf(m[h], __shfl_xor(m[h], 1));
      m[h] = fmaxf(m[h], __shfl_xor(m[h], 2));
      m[h] = fmaxf(m[h], __shfl_xor(m[h], 4));
    }
    // exp in place + local sums
    float s[4] = {0.f,0.f,0.f,0.f};
    if (q < 7) {
#pragma unroll
      for (int h=0;h<4;h++)
#pragma unroll
        for (int i=0;i<7;i++) {
          float ev = __expf(e[h][i] - m[h]);
          e[h][i] = ev;
          s[h] += ev;
        }
    }
#pragma unroll
    for (int h=0;h<4;h++) {
      s[h] += __shfl_xor(s[h], 1);
      s[h] += __shfl_xor(s[h], 2);
      s[h] += __shfl_xor(s[h], 4);
    }
    float gos[4];
#pragma unroll
    for (int h=0;h<4;h++) gos[h] = gate[h]*__builtin_amdgcn_rcpf(s[h]);
    // weighted 7-tap row sum from register exps
    float r0=0.f, r1=0.f, r2=0.f;
    if (q < 7) {
      int ny = min(max(byi + q - 3,0),HL-1);
#pragma unroll
      for (int i=0;i<7;i++) {
        int nx = min(max(bxi+i-3,0),WL-1);
        float wq = gos[0]*e[0][i] + gos[1]*e[1][i] + gos[2]*e[2][i] + gos[3]*e[3][i];
        int o = ny*WL + nx;
        r0 += wq*lr[o]; r1 += wq*lr[LRPIX+o]; r2 += wq*lr[2*LRPIX+o];
      }
    }
#pragma unroll
    for (int msk=1; msk<8; msk<<=1) {
      r0 += __shfl_xor(r0, msk);
      r1 += __shfl_xor(r1, msk);
      r2 += __shfl_xor(r2, msk);
    }
    if (q == 0) {
      int n = n0 + p;
      res0[n] = r0; res0[NPIX+n] = r1; res0[2*NPIX+n] = r2;
    }
  }
}

// ---- refiner conv0: groups=3, 2ch -> 16ch, GELU; out [3][NPIX][16] --------
__global__ void rconv0(const float* __restrict__ lrup, const float* __restrict__ res0,
                       const float* __restrict__ w, const float* __restrict__ bias,
                       float* __restrict__ out) {
  __shared__ float wl[288];      // [tap][ic2][oc16]
  int tid = threadIdx.x;
  int g = blockIdx.y;
  for (int idx = tid; idx < 288; idx += 256) {
    int o = idx/18, r = idx - o*18, ic = r/9, tap = r - ic*9;
    wl[tap*32 + ic*16 + o] = w[((g*16+o)*2+ic)*9 + tap];
  }
  __syncthreads();
  int p = blockIdx.x*blockDim.x + tid;
  int y = p / WH, x = p % WH;
  float acc[16];
#pragma unroll
  for (int o=0;o<16;o++) acc[o] = bias[g*16+o];
#pragma unroll
  for (int ky=0;ky<3;ky++) {
    int yy = y+ky-1;
    if (yy<0||yy>=HH) continue;
#pragma unroll
    for (int kx=0;kx<3;kx++) {
      int xx = x+kx-1;
      if (xx<0||xx>=WH) continue;
      int o0 = yy*WH+xx, tap = ky*3+kx;
#pragma unroll
      for (int ic=0; ic<2; ic++) {
        float v = (ic==0 ? lrup : res0)[g*NPIX + o0];
        const f32x4* wb = (const f32x4*)&wl[tap*32 + ic*16];
#pragma unroll
        for (int ov=0; ov<4; ov++) {
          f32x4 wv = wb[ov];
#pragma unroll
          for (int oo=0; oo<4; oo++) acc[ov*4+oo] += v*wv[oo];
        }
      }
    }
  }
  float* dst = out + (g*NPIX + p)*16;   // dense 64B/lane, fully coalesced
#pragma unroll
  for (int o=0;o<16;o++) dst[o] = gelu_f(acc[o]);
}

// ---- refiner conv1: groups=3, 16->16, GELU; [3][NPIX][16]; LDS weights ----
__global__ void rconv1(const float* __restrict__ hr0, const float* __restrict__ w,
                       const float* __restrict__ bias, float* __restrict__ out) {
  __shared__ float wl[2304];     // [tap][ic16][oc16] 9.2 KB
  int tid = threadIdx.x;
  int g = blockIdx.y;
  const float* wsrc = w + g*2304;   // [16 oc][16 ic][9 tap]
#pragma unroll
  for (int i=0;i<9;i++) {
    int idx = tid + i*256;
    int o = idx/144, r = idx - o*144, ic = r/9, tap = r - ic*9;
    wl[tap*256 + ic*16 + o] = wsrc[idx];
  }
  __syncthreads();
  int p = blockIdx.x*blockDim.x + tid;
  int y = p / WH, x = p % WH;
  const float* src_base = hr0 + g*NPIX*16;
  float acc[16];
#pragma unroll
  for (int o=0;o<16;o++) acc[o] = bias[g*16+o];
#pragma unroll
  for (int ky=0;ky<3;ky++) {
    int yy = y+ky-1;
    if (yy<0||yy>=HH) continue;
#pragma unroll
    for (int kx=0;kx<3;kx++) {
      int xx = x+kx-1;
      if (xx<0||xx>=WH) continue;
      const f32x4* src = (const f32x4*)&src_base[(yy*WH+xx)*16];   // 64B/lane dense
      const float* wt = &wl[(ky*3+kx)*256];
#pragma unroll
      for (int icv=0; icv<4; icv++) {
        f32x4 v = src[icv];
#pragma unroll
        for (int j=0;j<4;j++) {
          const f32x4* wb = (const f32x4*)&wt[(icv*4+j)*16];
#pragma unroll
          for (int ov=0; ov<4; ov++) {
            f32x4 wv = wb[ov];
#pragma unroll
            for (int oo=0; oo<4; oo++) acc[ov*4+oo] += v[j]*wv[oo];
          }
        }
      }
    }
  }
  float* dst = out + (g*NPIX + p)*16;
#pragma unroll
  for (int o=0;o<16;o++) dst[o] = gelu_f(acc[o]);
}

// --- refiner conv2 (16->1 per group) + sr + gray fusion + clip; [3][NPIX][16]
__global__ void rconv2_fuse(const float* __restrict__ hr1, const float* __restrict__ lrup,
                            const float* __restrict__ res0, const float* __restrict__ w,
                            const float* __restrict__ bias, float* __restrict__ out) {
  __shared__ float wl[432];      // [tap][c][ic16]
  int tid = threadIdx.x;
  for (int idx = tid; idx < 432; idx += 256) {
    int c = idx/144, r = idx - c*144, ic = r/9, tap = r - ic*9;
    wl[tap*48 + c*16 + ic] = w[idx];
  }
  __syncthreads();
  int p = blockIdx.x*blockDim.x + tid;
  if (p >= NPIX) return;
  int y = p / WH, x = p % WH;
  float acc3[3];
#pragma unroll
  for (int c=0;c<3;c++) acc3[c] = bias[c];
#pragma unroll
  for (int ky=0;ky<3;ky++) {
    int yy=y+ky-1; if (yy<0||yy>=HH) continue;
#pragma unroll
    for (int kx=0;kx<3;kx++) {
      int xx=x+kx-1; if (xx<0||xx>=WH) continue;
      int o0 = yy*WH+xx;
      const float* wt = &wl[(ky*3+kx)*48];
#pragma unroll
      for (int c=0;c<3;c++) {
        const f32x4* src = (const f32x4*)&hr1[(c*NPIX + o0)*16];
#pragma unroll
        for (int icv=0; icv<4; icv++) {
          f32x4 v = src[icv];
          f32x4 wv = *(const f32x4*)&wt[c*16 + icv*4];
          acc3[c] += v[0]*wv[0] + v[1]*wv[1] + v[2]*wv[2] + v[3]*wv[3];
        }
      }
    }
  }
  float sr[3], lu[3];
#pragma unroll
  for (int c=0;c<3;c++) {
    float l = lrup[c*NPIX+p];
    lu[c]=l;
    float srv = l + res0[c*NPIX+p] + acc3[c];
    sr[c] = fminf(fmaxf(srv,0.f),1.f);
  }
  float delta = 0.2989f*(sr[0]-lu[0]) + 0.587f*(sr[1]-lu[1]) + 0.114f*(sr[2]-lu[2]);
#pragma unroll
  for (int c=0;c<3;c++)
    out[c*NPIX+p] = fminf(fmaxf(lu[c]+delta,0.f),1.f);
}

// ---------------------------------------------------------------------------
extern "C" void kernel_launch(void* const* d_in, const int* in_sizes, int n_in,
                              void* d_out, int out_size, void* d_ws, size_t ws_size,
                              hipStream_t stream) {
  const float* lr     = (const float*)d_in[0];
  const float* enc_w0 = (const float*)d_in[1];
  const float* enc_b0 = (const float*)d_in[2];
  const float* enc_wh = (const float*)d_in[3];
  const float* enc_bh = (const float*)d_in[4];
  const float* mlp_w0 = (const float*)d_in[5];
  const float* mlp_b0 = (const float*)d_in[6];
  const float* mlp_wh = (const float*)d_in[7];
  const float* mlp_bh = (const float*)d_in[8];
  const float* kern_w = (const float*)d_in[9];
  const float* kern_b = (const float*)d_in[10];
  const float* gate_w = (const float*)d_in[11];
  const float* gate_b = (const float*)d_in[12];
  const float* ref_w0 = (const float*)d_in[13];
  const float* ref_b0 = (const float*)d_in[14];
  const float* ref_w1 = (const float*)d_in[15];
  const float* ref_b1 = (const float*)d_in[16];
  const float* ref_w2 = (const float*)d_in[17];
  const float* ref_b2 = (const float*)d_in[18];
  float* out = (float*)d_out;
  float* ws = (float*)d_ws;

  float* f_a  = ws;                 // 409600 floats, NHWC [6400][64]
  float* f_b  = ws + 409600;        // 409600, NHWC
  float* lrup = ws + 819200;        // 307200, NCHW [3][NPIX]
  float* res0 = ws + 1126400;       // 307200, NCHW
  float* hr0  = ws + 1433600;       // 4915200, [3][NPIX][16]
  float* hr1  = ws + 6348800;       // 4915200, [3][NPIX][16]

  _Float16* Wt0 = (_Float16*)f_a;   // 360448 halfs = 704 KB in f_a region
  _Float16* Wth = Wt0 + 32768;
  _Float16* Whd = Wth + 4*65536;

  enc_conv0<<<dim3(25,8), 256, 0, stream>>>(lr, enc_w0, enc_b0, f_a);
  enc_convh<<<dim3(50,8), 128, 0, stream>>>(f_a, enc_wh + 0*36864, enc_bh + 0,   f_b);
  enc_convh<<<dim3(50,8), 128, 0, stream>>>(f_b, enc_wh + 1*36864, enc_bh + 64,  f_a);
  enc_convh<<<dim3(50,8), 128, 0, stream>>>(f_a, enc_wh + 2*36864, enc_bh + 128, f_b);

  bicubic_up<<<1200, 256, 0, stream>>>(lr, lrup);

  // f_a now dead -> build packed fp16 weights there
  prep_weights<<<1408, 256, 0, stream>>>(mlp_w0, mlp_wh, kern_w, gate_w, Wt0);

  pixel_mlp2<<<1600, PMT, 0, stream>>>(f_b, lr, Wt0, mlp_b0, Wth, mlp_bh,
                                       Whd, kern_b, gate_b, res0);

  rconv0<<<dim3(400,3), 256, 0, stream>>>(lrup, res0, ref_w0, ref_b0, hr0);
  rconv1<<<dim3(400,3), 256, 0, stream>>>(hr0, ref_w1, ref_b1, hr1);
  rconv2_fuse<<<400, 256, 0, stream>>>(hr1, lrup, res0, ref_w2, ref_b2, out);
}

// Round 14
// 279.681 us; speedup vs baseline: 1.0111x; 1.0111x over previous
//
#include <hip/hip_runtime.h>
#include <math.h>

// ---------------------------------------------------------------------------
// SRModel. Round 14 = Round 11 structure + head logits kept in FP32 (LDS
// buffer aliasing hA+hB, extra barrier after head's hA reads). Rationale:
// R11 source passed at 0.015625 and the IDENTICAL R13 source failed at
// 0.0234 -> worst-pixel error sits at the threshold boundary (0.015625 is
// also the pure-fp32 round-1 score = jax-vs-np floor) and environment-level
// ulp variance flips it. fp16 logit quantization is our dominant added
// differential error into the softmax (~1e-2 after refiner amplification);
// removing it buys the margin.
// ---------------------------------------------------------------------------

#define HL 80
#define WL 80
#define HH 320
#define WH 320
#define NPIX (HH*WH)      // 102400
#define LRPIX (HL*WL)     // 6400
#define HID 256
#define K2 49

typedef _Float16 half8 __attribute__((ext_vector_type(8)));
typedef _Float16 half4 __attribute__((ext_vector_type(4)));
typedef float f32x4 __attribute__((ext_vector_type(4)));

__device__ __forceinline__ float gelu_f(float x) {
  float u = __builtin_fmaf(0.044715f*x, x*x, x);
  float e = __expf(-1.5957691216057308f * u);
  return x * __builtin_amdgcn_rcpf(1.0f + e);
}

__device__ __forceinline__ float keys_cubic(float x) {
  x = fabsf(x);
  if (x >= 2.0f) return 0.0f;
  if (x >= 1.0f) return ((-0.5f*x + 2.5f)*x - 4.0f)*x + 2.0f;
  return ((1.5f*x - 2.5f)*x)*x + 1.0f;
}

// -------- encoder conv0: lr NCHW [3][LRPIX] -> NHWC out [LRPIX][64] --------
__global__ void enc_conv0(const float* __restrict__ in, const float* __restrict__ w,
                          const float* __restrict__ bias, float* __restrict__ out) {
  __shared__ float wl[216];
  int tid = threadIdx.x;
  int chunk = blockIdx.y;
  if (tid < 216) {
    int o = tid/27, r = tid - o*27, ic = r/9, tap = r - ic*9;
    wl[tap*24 + ic*8 + o] = w[((chunk*8+o)*3+ic)*9 + tap];
  }
  __syncthreads();
  int pix = blockIdx.x*blockDim.x + tid;
  int y = pix / WL, x = pix % WL;
  float acc[8];
#pragma unroll
  for (int o=0;o<8;o++) acc[o] = bias[chunk*8+o];
#pragma unroll
  for (int ky=0; ky<3; ky++) {
    int yy = y+ky-1;
    if (yy < 0 || yy >= HL) continue;
#pragma unroll
    for (int kx=0; kx<3; kx++) {
      int xx = x+kx-1;
      if (xx < 0 || xx >= WL) continue;
      int o0 = yy*WL+xx, tap = ky*3+kx;
#pragma unroll
      for (int ic=0; ic<3; ic++) {
        float v = in[ic*LRPIX + o0];
        const f32x4* wb = (const f32x4*)&wl[tap*24 + ic*8];
        f32x4 w0 = wb[0], w1 = wb[1];
#pragma unroll
        for (int o=0;o<4;o++) { acc[o] += v*w0[o]; acc[o+4] += v*w1[o]; }
      }
    }
  }
#pragma unroll
  for (int o=0;o<8;o++)
    out[pix*64 + chunk*8 + o] = gelu_f(acc[o]);
}

// -------- encoder hidden conv: NHWC in -> NHWC out; LDS weights ------------
__global__ void enc_convh(const float* __restrict__ in, const float* __restrict__ w,
                          const float* __restrict__ bias, float* __restrict__ out) {
  __shared__ float wl[4608];
  int tid = threadIdx.x;
  int chunk = blockIdx.y;
  const float* wsrc = w + chunk*8*576;     // [8 oc][64 ic][9 tap]
#pragma unroll
  for (int i=0;i<36;i++) {
    int idx = tid + i*128;
    int o = idx/576, r = idx - o*576, ic = r/9, tap = r - ic*9;
    wl[tap*512 + ic*8 + o] = wsrc[idx];
  }
  __syncthreads();
  int pix = blockIdx.x*128 + tid;
  int y = pix / WL, x = pix % WL;
  float acc[8];
#pragma unroll
  for (int o=0;o<8;o++) acc[o] = bias[chunk*8+o];
#pragma unroll
  for (int ky=0; ky<3; ky++) {
    int yy = y+ky-1;
    if (yy < 0 || yy >= HL) continue;
#pragma unroll
    for (int kx=0; kx<3; kx++) {
      int xx = x+kx-1;
      if (xx < 0 || xx >= WL) continue;
      const f32x4* src = (const f32x4*)&in[(yy*WL+xx)*64];
      const float* wt = &wl[(ky*3+kx)*512];
#pragma unroll
      for (int icv=0; icv<16; icv++) {
        f32x4 v = src[icv];
#pragma unroll
        for (int j=0;j<4;j++) {
          const f32x4* wb = (const f32x4*)&wt[(icv*4+j)*8];
          f32x4 w0 = wb[0], w1 = wb[1];
#pragma unroll
          for (int o=0;o<4;o++) { acc[o] += v[j]*w0[o]; acc[4+o] += v[j]*w1[o]; }
        }
      }
    }
  }
#pragma unroll
  for (int o=0;o<8;o++)
    out[pix*64 + chunk*8 + o] = gelu_f(acc[o]);
}

// ---------------- bicubic upsample (matches jax.image.resize 'cubic') ------
__global__ void bicubic_up(const float* __restrict__ lr, float* __restrict__ up) {
  int id = blockIdx.x*blockDim.x + threadIdx.x;
  if (id >= 3*NPIX) return;
  int c = id / NPIX, p = id % NPIX;
  int hy = p / WH, hx = p % WH;
  float sx = (hx+0.5f)*0.25f - 0.5f;
  float sy = (hy+0.5f)*0.25f - 0.5f;
  int bx = (int)floorf(sx), by = (int)floorf(sy);
  float wx[4], wy[4];
  int ix[4], iy[4];
  float sumx = 0.f, sumy = 0.f;
#pragma unroll
  for (int i=0;i<4;i++) {
    int j = bx-1+i;
    float wv = (j>=0 && j<WL) ? keys_cubic(sx - (float)j) : 0.f;
    wx[i] = wv; ix[i] = min(max(j,0), WL-1); sumx += wv;
    j = by-1+i;
    wv = (j>=0 && j<HL) ? keys_cubic(sy - (float)j) : 0.f;
    wy[i] = wv; iy[i] = min(max(j,0), HL-1); sumy += wv;
  }
  float inx = __builtin_amdgcn_rcpf(sumx), iny = __builtin_amdgcn_rcpf(sumy);
  const float* src = lr + c*LRPIX;
  float acc = 0.f;
#pragma unroll
  for (int i=0;i<4;i++) {
    float rowv = 0.f;
#pragma unroll
    for (int j=0;j<4;j++) rowv += wx[j]*src[iy[i]*WL + ix[j]];
    acc += wy[i]*rowv;
  }
  up[c*NPIX + p] = acc * inx * iny;
}

// ------- weight prep: fp32 -> fp16, packed in MFMA fragment order ----------
__global__ void prep_weights(const float* __restrict__ w0, const float* __restrict__ wh,
                             const float* __restrict__ kw, const float* __restrict__ gw,
                             _Float16* __restrict__ out) {
  int idx = blockIdx.x*blockDim.x + threadIdx.x;
  int e = idx & 7, lane = (idx>>3)&63;
  int kf = (lane>>4)*8 + e;
  int nf = lane & 15;
  if (idx < 32768) {
    int t = idx >> 9;
    int kt = t & 3, nt = t >> 2;
    int k = kt*32 + kf, n = nt*16 + nf;
    out[idx] = (_Float16)((k < 106) ? w0[k*HID + n] : 0.f);
  } else if (idx < 32768 + 4*65536) {
    int r = idx - 32768;
    int L = r >> 16; r &= 65535;
    int t = r >> 9;
    int kt = t & 7, nt = t >> 3;
    int k = kt*32 + kf, n = nt*16 + nf;
    out[idx] = (_Float16)wh[(L*HID + k)*HID + n];
  } else if (idx < 32768 + 5*65536) {
    int r = idx - (32768 + 4*65536);
    int t = r >> 9;
    int kt = t & 7, nt = t >> 3;
    int k = kt*32 + kf, n = nt*16 + nf;
    float v = (n < 196) ? kw[k*196 + n] : ((n < 200) ? gw[k*4 + (n-196)] : 0.f);
    out[idx] = (_Float16)v;
  }
}

// ---------------- fused per-pixel MLP (MFMA) + softmax + 7x7 sum ------------
// x/h in B-fragment-linear LDS: buf[((pt*NKS+ks)*64 + lane)*8 + e].
// Head logits stored FP32 in kfb (aliases hA+hB, 51.2KB of 64KB arena).
#define PMT 512
__global__ __launch_bounds__(PMT, 4)
void pixel_mlp2(const float* __restrict__ f, const float* __restrict__ lr,
                const _Float16* __restrict__ Wt0, const float* __restrict__ b0,
                const _Float16* __restrict__ Wth, const float* __restrict__ bh,
                const _Float16* __restrict__ Whd, const float* __restrict__ kb,
                const float* __restrict__ gb, float* __restrict__ res0) {
  __shared__ _Float16 smem[8192 + 16384 + 16384];   // x | hA | hB  = 80 KB
  _Float16* x_lds = smem;            // frag layout, NKS=4
  _Float16* hA    = smem + 8192;     // frag layout, NKS=8
  _Float16* hB    = smem + 8192 + 16384;
  float*    kfb   = (float*)hA;      // fp32 logits [64][200], aliases hA+hB

  const int tid = threadIdx.x;
  const int lane = tid & 63;
  const int wave = tid >> 6;
  const int n0 = blockIdx.x * 64;
  const int hy = n0 / WH;                       // block-uniform (64 | 320)
  const int hx0 = n0 % WH;
  const float ly = (hy+0.5f)*0.25f - 0.5f;
  const int byi = min(max((int)floorf(ly),0), HL-1);
  const float fy = ly - floorf(ly);
  const float hyn = (hy+0.5f)/320.0f*2.0f - 1.0f;   // reference rounding path

  // ---- Phase A, part 1: cfeat (k<64) from NHWC f -> frag layout ----
#pragma unroll
  for (int i = 0; i < 8; i++) {
    int p = (tid>>6) + i*8;            // wave-uniform pixel
    int k = lane;
    int hx = hx0 + p;
    float lx = (hx+0.5f)*0.25f - 0.5f;
    int bxi = min(max((int)floorf(lx),0), WL-1);
    float v = f[(byi*WL + bxi)*64 + k];
    int ld = (p & 15) | (((k >> 3) & 3) << 4);
    x_lds[(((p>>4)*4 + (k>>5))*64 + ld)*8 + (k & 7)] = (_Float16)v;
  }
  // ---- Phase A, part 2: PE (libm trig, reference-exact fp32 rounding) ----
#pragma unroll
  for (int i = 0; i < 8; i++) {
    int p = (tid>>6) + i*8;
    int k = 64 + lane;
    int hx = hx0 + p;
    float v = 0.f;
    if (k < 104) {
      int band = (k-64) >> 2, r = (k-64) & 3;
      float freq = (float)(1<<band) * 3.14159265358979323846f;
      float hxn = (hx+0.5f)/320.0f*2.0f - 1.0f;
      float arg = ((r<2) ? hxn : hyn) * freq;
      v = (r&1) ? cosf(arg) : sinf(arg);
    } else if (k == 104) {
      float lx = (hx+0.5f)*0.25f - 0.5f;
      v = lx - floorf(lx);
    } else if (k == 105) {
      v = fy;
    }
    int ld = (p & 15) | (((k >> 3) & 3) << 4);
    x_lds[(((p>>4)*4 + (k>>5))*64 + ld)*8 + (k & 7)] = (_Float16)v;
  }
  __syncthreads();

  const int col  = lane & 15;
  const int g    = lane >> 4;
  const int rbase = g*4;
  const int ld0 = (lane & 15) | (((g>>1)    ) << 4);        // nt=0
  const int ld1 = (lane & 15) | (((2 + (g>>1)) & 3) << 4);  // nt=1
  const int e0  = 4*(g & 1);

  f32x4 acc[2][4];
  const f32x4 vzero = {0.f,0.f,0.f,0.f};
  const half8* A0 = (const half8*)Wt0;
  const half8* AH = (const half8*)Whd;

  // ---- layer 0: W0(A) x x(B) -> hA ----
#pragma unroll
  for (int nt=0;nt<2;nt++)
#pragma unroll
    for (int pt=0;pt<4;pt++) acc[nt][pt] = vzero;
#pragma unroll
  for (int ks=0; ks<4; ks++) {
    half8 aw[2], bx[4];
#pragma unroll
    for (int nt=0;nt<2;nt++)
      aw[nt] = A0[((wave*2+nt)*4 + ks)*64 + lane];
#pragma unroll
    for (int pt=0;pt<4;pt++)
      bx[pt] = *(const half8*)&x_lds[((pt*4 + ks)*64 + lane)*8];   // linear
#pragma unroll
    for (int nt=0;nt<2;nt++)
#pragma unroll
      for (int pt=0;pt<4;pt++)
        acc[nt][pt] = __builtin_amdgcn_mfma_f32_16x16x32_f16(aw[nt], bx[pt], acc[nt][pt], 0,0,0);
  }
#pragma unroll
  for (int nt=0;nt<2;nt++) {
    int nbase = wave*32 + nt*16 + rbase;
    f32x4 bb = *(const f32x4*)&b0[nbase];
    int ld = nt ? ld1 : ld0;
#pragma unroll
    for (int pt=0;pt<4;pt++) {
      half4 hv;
      hv[0] = (_Float16)gelu_f(acc[nt][pt][0] + bb[0]);
      hv[1] = (_Float16)gelu_f(acc[nt][pt][1] + bb[1]);
      hv[2] = (_Float16)gelu_f(acc[nt][pt][2] + bb[2]);
      hv[3] = (_Float16)gelu_f(acc[nt][pt][3] + bb[3]);
      *(half4*)&hA[((pt*8 + wave)*64 + ld)*8 + e0] = hv;
    }
  }
  __syncthreads();

  // ---- 4 hidden layers: ping-pong hA <-> hB (frag layout, NKS=8) ----
  for (int L=0; L<4; L++) {
    const _Float16* hs = (L & 1) ? hB : hA;
    _Float16*       hd = (L & 1) ? hA : hB;
    const half8* AL = (const half8*)(Wth + L*65536);
#pragma unroll
    for (int nt=0;nt<2;nt++)
#pragma unroll
      for (int pt=0;pt<4;pt++) acc[nt][pt] = vzero;
#pragma unroll
    for (int ks=0; ks<8; ks++) {
      half8 aw[2], bx[4];
#pragma unroll
      for (int nt=0;nt<2;nt++)
        aw[nt] = AL[((wave*2+nt)*8 + ks)*64 + lane];
#pragma unroll
      for (int pt=0;pt<4;pt++)
        bx[pt] = *(const half8*)&hs[((pt*8 + ks)*64 + lane)*8];    // linear
#pragma unroll
      for (int nt=0;nt<2;nt++)
#pragma unroll
        for (int pt=0;pt<4;pt++)
          acc[nt][pt] = __builtin_amdgcn_mfma_f32_16x16x32_f16(aw[nt], bx[pt], acc[nt][pt], 0,0,0);
    }
#pragma unroll
    for (int nt=0;nt<2;nt++) {
      int nbase = wave*32 + nt*16 + rbase;
      f32x4 bb = *(const f32x4*)&bh[L*HID + nbase];
      int ld = nt ? ld1 : ld0;
#pragma unroll
      for (int pt=0;pt<4;pt++) {
        half4 hv;
        hv[0] = (_Float16)gelu_f(acc[nt][pt][0] + bb[0]);
        hv[1] = (_Float16)gelu_f(acc[nt][pt][1] + bb[1]);
        hv[2] = (_Float16)gelu_f(acc[nt][pt][2] + bb[2]);
        hv[3] = (_Float16)gelu_f(acc[nt][pt][3] + bb[3]);
        *(half4*)&hd[((pt*8 + wave)*64 + ld)*8 + e0] = hv;
      }
    }
    __syncthreads();
  }

  // ---- head: Whd(A) x hA(B) -> 200 fp32 logits/pixel into kfb[pix][200] ----
#pragma unroll
  for (int nt=0;nt<2;nt++)
#pragma unroll
    for (int pt=0;pt<4;pt++) acc[nt][pt] = vzero;
#pragma unroll
  for (int ks=0; ks<8; ks++) {
    half8 aw[2], bx[4];
#pragma unroll
    for (int nt=0;nt<2;nt++)
      aw[nt] = AH[((wave*2+nt)*8 + ks)*64 + lane];
#pragma unroll
    for (int pt=0;pt<4;pt++)
      bx[pt] = *(const half8*)&hA[((pt*8 + ks)*64 + lane)*8];      // linear
#pragma unroll
    for (int nt=0;nt<2;nt++)
#pragma unroll
      for (int pt=0;pt<4;pt++)
        acc[nt][pt] = __builtin_amdgcn_mfma_f32_16x16x32_f16(aw[nt], bx[pt], acc[nt][pt], 0,0,0);
  }
  __syncthreads();   // ALL waves done reading hA/hB before fp32 alias writes
#pragma unroll
  for (int nt=0;nt<2;nt++) {
    int jb = wave*32 + nt*16 + rbase;
    if (jb < 200) {
      const float* bp = (jb < 196) ? (kb + jb) : (gb + (jb - 196));
      f32x4 bb = *(const f32x4*)bp;
#pragma unroll
      for (int pt=0;pt<4;pt++) {
        int pix = pt*16 + col;
        float* kp = &kfb[pix*200 + jb];
        kp[0] = acc[nt][pt][0] + bb[0];
        kp[1] = acc[nt][pt][1] + bb[1];
        kp[2] = acc[nt][pt][2] + bb[2];
        kp[3] = acc[nt][pt][3] + bb[3];
      }
    }
  }
  __syncthreads();

  // ---- Phase E (tap-split): thread q owns kernel row q; fp32 logits ----
  {
    int p = tid >> 3, q = tid & 7;
    int hx = hx0 + p;
    float lx = (hx+0.5f)*0.25f - 0.5f;
    int bxi = min(max((int)floorf(lx),0), WL-1);
    const float* kp = &kfb[p*200];
    // gate softmax (redundant on 8 threads)
    float g0=kp[196], g1=kp[197], g2=kp[198], g3=kp[199];
    float gm = fmaxf(fmaxf(g0,g1), fmaxf(g2,g3));
    g0=__expf(g0-gm); g1=__expf(g1-gm); g2=__expf(g2-gm); g3=__expf(g3-gm);
    float gs = __builtin_amdgcn_rcpf(g0+g1+g2+g3);
    float gate[4] = {g0*gs, g1*gs, g2*gs, g3*gs};
    // load 28 logits into regs + per-head local max
    float e[4][7];
    float m[4];
#pragma unroll
    for (int h=0;h<4;h++) m[h] = -1e30f;
    if (q < 7) {
#pragma unroll
      for (int h=0;h<4;h++)
#pragma unroll
        for (int i=0;i<7;i++) {
          float v = kp[h*K2 + q*7 + i];
          e[h][i] = v;
          m[h] = fmaxf(m[h], v);
        }
    }
#pragma unroll
    for (int h=0;h<4;h++) {
      m[h] = fmaxf(m[h], __shfl_xor(m[h], 1));
      m[h] = fmaxf(m[h], __shfl_xor(m[h], 2));
      m[h] = fmaxf(m[h], __shfl_xor(m[h], 4));
    }
    // exp in place + local sums
    float s[4] = {0.f,0.f,0.f,0.f};
    if (q < 7) {
#pragma unroll
      for (int h=0;h<4;h++)
#pragma unroll
        for (int i=0;i<7;i++) {
          float ev = __expf(e[h][i] - m[h]);
          e[h][i] = ev;
          s[h] += ev;
        }
    }
#pragma unroll
    for (int h=0;h<4;h++) {
      s[h] += __shfl_xor(s[h], 1);
      s[h] += __shfl_xor(s[h], 2);
      s[h] += __shfl_xor(s[h], 4);
    }
    float gos[4];
#pragma unroll
    for (int h=0;h<4;h++) gos[h] = gate[h]*__builtin_amdgcn_rcpf(s[h]);
    // weighted 7-tap row sum from register exps
    float r0=0.f, r1=0.f, r2=0.f;
    if (q < 7) {
      int ny = min(max(byi + q - 3,0),HL-1);
#pragma unroll
      for (int i=0;i<7;i++) {
        int nx = min(max(bxi+i-3,0),WL-1);
        float wq = gos[0]*e[0][i] + gos[1]*e[1][i] + gos[2]*e[2][i] + gos[3]*e[3][i];
        int o = ny*WL + nx;
        r0 += wq*lr[o]; r1 += wq*lr[LRPIX+o]; r2 += wq*lr[2*LRPIX+o];
      }
    }
#pragma unroll
    for (int msk=1; msk<8; msk<<=1) {
      r0 += __shfl_xor(r0, msk);
      r1 += __shfl_xor(r1, msk);
      r2 += __shfl_xor(r2, msk);
    }
    if (q == 0) {
      int n = n0 + p;
      res0[n] = r0; res0[NPIX+n] = r1; res0[2*NPIX+n] = r2;
    }
  }
}

// ---- refiner conv0: groups=3, 2ch -> 16ch, GELU; out [3][NPIX][16] --------
__global__ void rconv0(const float* __restrict__ lrup, const float* __restrict__ res0,
                       const float* __restrict__ w, const float* __restrict__ bias,
                       float* __restrict__ out) {
  __shared__ float wl[288];      // [tap][ic2][oc16]
  int tid = threadIdx.x;
  int g = blockIdx.y;
  for (int idx = tid; idx < 288; idx += 256) {
    int o = idx/18, r = idx - o*18, ic = r/9, tap = r - ic*9;
    wl[tap*32 + ic*16 + o] = w[((g*16+o)*2+ic)*9 + tap];
  }
  __syncthreads();
  int p = blockIdx.x*blockDim.x + tid;
  int y = p / WH, x = p % WH;
  float acc[16];
#pragma unroll
  for (int o=0;o<16;o++) acc[o] = bias[g*16+o];
#pragma unroll
  for (int ky=0;ky<3;ky++) {
    int yy = y+ky-1;
    if (yy<0||yy>=HH) continue;
#pragma unroll
    for (int kx=0;kx<3;kx++) {
      int xx = x+kx-1;
      if (xx<0||xx>=WH) continue;
      int o0 = yy*WH+xx, tap = ky*3+kx;
#pragma unroll
      for (int ic=0; ic<2; ic++) {
        float v = (ic==0 ? lrup : res0)[g*NPIX + o0];
        const f32x4* wb = (const f32x4*)&wl[tap*32 + ic*16];
#pragma unroll
        for (int ov=0; ov<4; ov++) {
          f32x4 wv = wb[ov];
#pragma unroll
          for (int oo=0; oo<4; oo++) acc[ov*4+oo] += v*wv[oo];
        }
      }
    }
  }
  float* dst = out + (g*NPIX + p)*16;   // dense 64B/lane, fully coalesced
#pragma unroll
  for (int o=0;o<16;o++) dst[o] = gelu_f(acc[o]);
}

// ---- refiner conv1: groups=3, 16->16, GELU; [3][NPIX][16]; LDS weights ----
__global__ void rconv1(const float* __restrict__ hr0, const float* __restrict__ w,
                       const float* __restrict__ bias, float* __restrict__ out) {
  __shared__ float wl[2304];     // [tap][ic16][oc16] 9.2 KB
  int tid = threadIdx.x;
  int g = blockIdx.y;
  const float* wsrc = w + g*2304;   // [16 oc][16 ic][9 tap]
#pragma unroll
  for (int i=0;i<9;i++) {
    int idx = tid + i*256;
    int o = idx/144, r = idx - o*144, ic = r/9, tap = r - ic*9;
    wl[tap*256 + ic*16 + o] = wsrc[idx];
  }
  __syncthreads();
  int p = blockIdx.x*blockDim.x + tid;
  int y = p / WH, x = p % WH;
  const float* src_base = hr0 + g*NPIX*16;
  float acc[16];
#pragma unroll
  for (int o=0;o<16;o++) acc[o] = bias[g*16+o];
#pragma unroll
  for (int ky=0;ky<3;ky++) {
    int yy = y+ky-1;
    if (yy<0||yy>=HH) continue;
#pragma unroll
    for (int kx=0;kx<3;kx++) {
      int xx = x+kx-1;
      if (xx<0||xx>=WH) continue;
      const f32x4* src = (const f32x4*)&src_base[(yy*WH+xx)*16];   // 64B/lane dense
      const float* wt = &wl[(ky*3+kx)*256];
#pragma unroll
      for (int icv=0; icv<4; icv++) {
        f32x4 v = src[icv];
#pragma unroll
        for (int j=0;j<4;j++) {
          const f32x4* wb = (const f32x4*)&wt[(icv*4+j)*16];
#pragma unroll
          for (int ov=0; ov<4; ov++) {
            f32x4 wv = wb[ov];
#pragma unroll
            for (int oo=0; oo<4; oo++) acc[ov*4+oo] += v[j]*wv[oo];
          }
        }
      }
    }
  }
  float* dst = out + (g*NPIX + p)*16;
#pragma unroll
  for (int o=0;o<16;o++) dst[o] = gelu_f(acc[o]);
}

// --- refiner conv2 (16->1 per group) + sr + gray fusion + clip; [3][NPIX][16]
__global__ void rconv2_fuse(const float* __restrict__ hr1, const float* __restrict__ lrup,
                            const float* __restrict__ res0, const float* __restrict__ w,
                            const float* __restrict__ bias, float* __restrict__ out) {
  __shared__ float wl[432];      // [tap][c][ic16]
  int tid = threadIdx.x;
  for (int idx = tid; idx < 432; idx += 256) {
    int c = idx/144, r = idx - c*144, ic = r/9, tap = r - ic*9;
    wl[tap*48 + c*16 + ic] = w[idx];
  }
  __syncthreads();
  int p = blockIdx.x*blockDim.x + tid;
  if (p >= NPIX) return;
  int y = p / WH, x = p % WH;
  float acc3[3];
#pragma unroll
  for (int c=0;c<3;c++) acc3[c] = bias[c];
#pragma unroll
  for (int ky=0;ky<3;ky++) {
    int yy=y+ky-1; if (yy<0||yy>=HH) continue;
#pragma unroll
    for (int kx=0;kx<3;kx++) {
      int xx=x+kx-1; if (xx<0||xx>=WH) continue;
      int o0 = yy*WH+xx;
      const float* wt = &wl[(ky*3+kx)*48];
#pragma unroll
      for (int c=0;c<3;c++) {
        const f32x4* src = (const f32x4*)&hr1[(c*NPIX + o0)*16];
#pragma unroll
        for (int icv=0; icv<4; icv++) {
          f32x4 v = src[icv];
          f32x4 wv = *(const f32x4*)&wt[c*16 + icv*4];
          acc3[c] += v[0]*wv[0] + v[1]*wv[1] + v[2]*wv[2] + v[3]*wv[3];
        }
      }
    }
  }
  float sr[3], lu[3];
#pragma unroll
  for (int c=0;c<3;c++) {
    float l = lrup[c*NPIX+p];
    lu[c]=l;
    float srv = l + res0[c*NPIX+p] + acc3[c];
    sr[c] = fminf(fmaxf(srv,0.f),1.f);
  }
  float delta = 0.2989f*(sr[0]-lu[0]) + 0.587f*(sr[1]-lu[1]) + 0.114f*(sr[2]-lu[2]);
#pragma unroll
  for (int c=0;c<3;c++)
    out[c*NPIX+p] = fminf(fmaxf(lu[c]+delta,0.f),1.f);
}

// ---------------------------------------------------------------------------
extern "C" void kernel_launch(void* const* d_in, const int* in_sizes, int n_in,
                              void* d_out, int out_size, void* d_ws, size_t ws_size,
                              hipStream_t stream) {
  const float* lr     = (const float*)d_in[0];
  const float* enc_w0 = (const float*)d_in[1];
  const float* enc_b0 = (const float*)d_in[2];
  const float* enc_wh = (const float*)d_in[3];
  const float* enc_bh = (const float*)d_in[4];
  const float* mlp_w0 = (const float*)d_in[5];
  const float* mlp_b0 = (const float*)d_in[6];
  const float* mlp_wh = (const float*)d_in[7];
  const float* mlp_bh = (const float*)d_in[8];
  const float* kern_w = (const float*)d_in[9];
  const float* kern_b = (const float*)d_in[10];
  const float* gate_w = (const float*)d_in[11];
  const float* gate_b = (const float*)d_in[12];
  const float* ref_w0 = (const float*)d_in[13];
  const float* ref_b0 = (const float*)d_in[14];
  const float* ref_w1 = (const float*)d_in[15];
  const float* ref_b1 = (const float*)d_in[16];
  const float* ref_w2 = (const float*)d_in[17];
  const float* ref_b2 = (const float*)d_in[18];
  float* out = (float*)d_out;
  float* ws = (float*)d_ws;

  float* f_a  = ws;                 // 409600 floats, NHWC [6400][64]
  float* f_b  = ws + 409600;        // 409600, NHWC
  float* lrup = ws + 819200;        // 307200, NCHW [3][NPIX]
  float* res0 = ws + 1126400;       // 307200, NCHW
  float* hr0  = ws + 1433600;       // 4915200, [3][NPIX][16]
  float* hr1  = ws + 6348800;       // 4915200, [3][NPIX][16]

  _Float16* Wt0 = (_Float16*)f_a;   // 360448 halfs = 704 KB in f_a region
  _Float16* Wth = Wt0 + 32768;
  _Float16* Whd = Wth + 4*65536;

  enc_conv0<<<dim3(25,8), 256, 0, stream>>>(lr, enc_w0, enc_b0, f_a);
  enc_convh<<<dim3(50,8), 128, 0, stream>>>(f_a, enc_wh + 0*36864, enc_bh + 0,   f_b);
  enc_convh<<<dim3(50,8), 128, 0, stream>>>(f_b, enc_wh + 1*36864, enc_bh + 64,  f_a);
  enc_convh<<<dim3(50,8), 128, 0, stream>>>(f_a, enc_wh + 2*36864, enc_bh + 128, f_b);

  bicubic_up<<<1200, 256, 0, stream>>>(lr, lrup);

  // f_a now dead -> build packed fp16 weights there
  prep_weights<<<1408, 256, 0, stream>>>(mlp_w0, mlp_wh, kern_w, gate_w, Wt0);

  pixel_mlp2<<<1600, PMT, 0, stream>>>(f_b, lr, Wt0, mlp_b0, Wth, mlp_bh,
                                       Whd, kern_b, gate_b, res0);

  rconv0<<<dim3(400,3), 256, 0, stream>>>(lrup, res0, ref_w0, ref_b0, hr0);
  rconv1<<<dim3(400,3), 256, 0, stream>>>(hr0, ref_w1, ref_b1, hr1);
  rconv2_fuse<<<400, 256, 0, stream>>>(hr1, lrup, res0, ref_w2, ref_b2, out);
}